// Round 15
// baseline (185.163 us; speedup 1.0000x reference)
//
#include <hip/hip_runtime.h>
#include <hip/hip_bf16.h>
#include <hip/hip_fp16.h>

// ---------- types ----------
typedef __attribute__((ext_vector_type(8))) short    bf16x8;  // 8 bf16 MFMA A/B frag
typedef __attribute__((ext_vector_type(4))) float    f32x4;   // MFMA C/D frag
typedef __attribute__((ext_vector_type(4))) _Float16 f16x4;   // 16x16x16 f16 frag
typedef __attribute__((ext_vector_type(8))) _Float16 f16x8;
typedef __attribute__((ext_vector_type(2))) __fp16   fp16x2_raw;  // cvt_pkrtz return type

typedef const void __attribute__((address_space(1))) gvoid_t;
typedef void __attribute__((address_space(3)))       lvoid_t;

static __device__ __forceinline__ void gload_lds16(const void* g, void* l) {
    // LDS dest = wave-uniform base + lane*16B; global src is per-lane.
    __builtin_amdgcn_global_load_lds((gvoid_t*)g, (lvoid_t*)l, 16, 0, 0);
}

static __device__ __forceinline__ short bfbits(float f) {
    union { __hip_bfloat16 h; short s; } u;
    u.h = __float2bfloat16(f);
    return u.s;
}

// RoPE rotation shared by GEMM epilogues. Reference quirk preserved:
// out[2i] = x0*sin(pe) - x1*cos(pe); out[2i+1] = x1*sin(pe) + x0*cos(pe).
static __device__ __forceinline__ float rope_val(float val, int col, int row, int Smask) {
    float other = __shfl_xor(val, 1);
    float theta = __expf(-0.28782313662425572f * (float)((col >> 1) & 31));
    float sp, cp;
    __sincosf((float)(row & Smask) * theta, &sp, &cp);
    return (col & 1) ? fmaf(val, sp, other * cp) : fmaf(val, sp, -other * cp);
}

// ---------- mega-prep: input cvt + 8 weight transposes + bias concats, one launch ----------
struct TJob { const float* src; __hip_bfloat16* dst; int K, N, tx; };
struct PrepArgs {
    const float* query; const float* key;
    __hip_bfloat16* q_bf; __hip_bfloat16* k_bf; int n8; int cvtBlocks; int tBlocks;
    TJob j[8]; int start[8];
    const float *b_dkv, *b_kr, *b_uk, *b_uv, *b_uq, *b_qr;
    float *bcat1, *bcat2, *bcat3;
};

__global__ __launch_bounds__(256) void prep_kernel(PrepArgs A) {
    __shared__ __hip_bfloat16 tile[64][72];
    int bid = blockIdx.x;
    if (bid < A.cvtBlocks) {
        int t = bid * 256 + threadIdx.x;
        const float* src;
        __hip_bfloat16* dst;
        int i;
        if (t < A.n8) { src = A.query; dst = A.q_bf; i = t; }
        else          { src = A.key;   dst = A.k_bf; i = t - A.n8; }
        float4 a = ((const float4*)src)[2 * i];
        float4 b = ((const float4*)src)[2 * i + 1];
        bf16x8 o;
        o[0] = bfbits(a.x); o[1] = bfbits(a.y); o[2] = bfbits(a.z); o[3] = bfbits(a.w);
        o[4] = bfbits(b.x); o[5] = bfbits(b.y); o[6] = bfbits(b.z); o[7] = bfbits(b.w);
        ((bf16x8*)dst)[i] = o;
        return;
    }
    bid -= A.cvtBlocks;
    if (bid < A.tBlocks) {
        int ji = 0;
#pragma unroll
        for (int k = 1; k < 8; ++k) if (bid >= A.start[k]) ji = k;
        const TJob J = A.j[ji];
        const int local = bid - A.start[ji];
        const int kb = (local % J.tx) * 64;
        const int nb = (local / J.tx) * 64;
        const int c  = threadIdx.x & 63;
        const int r0 = threadIdx.x >> 6;
        if (nb < J.N) {
#pragma unroll
            for (int i = 0; i < 16; ++i) {
                int r = r0 + i * 4;
                tile[r][c] = __float2bfloat16(J.src[(size_t)(kb + r) * J.N + nb + c]);
            }
            __syncthreads();
#pragma unroll
            for (int i = 0; i < 16; ++i) {
                int r = r0 + i * 4;
                J.dst[(size_t)(nb + r) * J.K + kb + c] = tile[c][r];
            }
        } else {
            __hip_bfloat16 z = __float2bfloat16(0.0f);
#pragma unroll
            for (int i = 0; i < 16; ++i) {
                int r = r0 + i * 4;
                J.dst[(size_t)(nb + r) * J.K + kb + c] = z;
            }
        }
        return;
    }
    bid -= A.tBlocks;
    int t = bid * 256 + threadIdx.x;
    if (t < 640) {
        A.bcat1[t] = (t < 512) ? A.b_dkv[t] : ((t - 512) < 64 ? A.b_kr[t - 512] : 0.0f);
    } else if (t < 2688) {
        int u = t - 640;
        A.bcat2[u] = (u < 1024) ? A.b_uq[u] : A.b_qr[u - 1024];
    } else if (t < 4736) {
        int u = t - 2688;
        A.bcat3[u] = (u < 1024) ? A.b_uk[u] : A.b_uv[u - 1024];
    }
}

// ---------- unified dual-job GEMM: 64x128 tile, BK=64, 3-buffer counted-vmcnt pipeline ----------
// T4 schedule: stage issues 6 global_load_lds per wave; main loop waits vmcnt(6)
// (only the OLDER stage must have landed -- newest 6 stay in flight across the
// barrier), raw s_barrier, issue stage(t+2), compute tile t. Final iter peeled
// with vmcnt(0). Never drains to 0 in the main loop (m97-stall fix).
// modes: 0 = bf16 -> C0
//        1 = f32  -> C0
//        3 = cols<1024 bf16 -> C0 (ktc); cols>=1024 -> C1 = vtcT [1024][Rtot] f16,
//            written TRANSPOSED via in-block LDS transpose
//        4 = bf16 -> C0, RoPE on cols>=1024 (qrope)
//        5 = bf16 -> C0, RoPE on cols in [512,576) (krope)
// LDS: 16B slot s of row r holds global slot s^(r&7) (pre-swizzled src, rule 21).
struct GJob {
    const __hip_bfloat16* A; const __hip_bfloat16* Bt; const float* bias;
    void* C0; void* C1; int N, K, lda, ldb, ldc; float scale; int mode;
};

__global__ __launch_bounds__(256) void gemm64(GJob j0, GJob j1, int split, int Smask, int Rtot) {
    __shared__ __align__(16) char smem[73728];             // sA 3x8KB | sB 3x16KB; T aliases
    __hip_bfloat16* sA = (__hip_bfloat16*)smem;            // [3][64*64]
    __hip_bfloat16* sB = (__hip_bfloat16*)(smem + 24576);  // [3][128*64]
    const GJob J  = (blockIdx.x < (unsigned)split) ? j0 : j1;
    const int bx  = (blockIdx.x < (unsigned)split) ? blockIdx.x : blockIdx.x - split;
    const int tid  = threadIdx.x;
    const int wid  = tid >> 6;
    const int lane = tid & 63;
    const int lr   = lane & 15;
    const int lg   = lane >> 4;
    const int mb   = blockIdx.y * 64;
    const int nb   = bx * 128;
    const int wr   = (wid >> 1) * 32;
    const int wc   = (wid & 1) * 64;

    auto stage = [&](int bufi, int k0) {
#pragma unroll
        for (int j = 0; j < 2; ++j) {  // A tile 64x64: 8 chunks of 1KB (8 rows), 2 per wave
            int c   = wid * 2 + j;
            int rho = c * 8 + (lane >> 3);
            int u   = (lane & 7) ^ (rho & 7);
            gload_lds16(J.A + (size_t)(mb + rho) * J.lda + (k0 + u * 8),
                        &sA[bufi * 4096 + c * 512]);
        }
#pragma unroll
        for (int j = 0; j < 4; ++j) {  // B tile 128x64: 16 chunks, 4 per wave
            int c   = wid * 4 + j;
            int rho = c * 8 + (lane >> 3);
            int u   = (lane & 7) ^ (rho & 7);
            gload_lds16(J.Bt + (size_t)(nb + rho) * J.ldb + (k0 + u * 8),
                        &sB[bufi * 8192 + c * 512]);
        }
    };

    f32x4 acc[2][4] = {};

    auto compute = [&](int bufi) {
#pragma unroll
        for (int kk = 0; kk < 2; ++kk) {
            bf16x8 af[2], bfr[4];
#pragma unroll
            for (int m = 0; m < 2; ++m) {
                int row = wr + m * 16 + lr;
                af[m] = *(const bf16x8*)&sA[bufi * 4096 + row * 64 + (((kk * 4 + lg) ^ (row & 7)) << 3)];
            }
#pragma unroll
            for (int n = 0; n < 4; ++n) {
                int row = wc + n * 16 + lr;
                bfr[n] = *(const bf16x8*)&sB[bufi * 8192 + row * 64 + (((kk * 4 + lg) ^ (row & 7)) << 3)];
            }
#pragma unroll
            for (int m = 0; m < 2; ++m)
#pragma unroll
                for (int n = 0; n < 4; ++n)
                    acc[m][n] = __builtin_amdgcn_mfma_f32_16x16x32_bf16(af[m], bfr[n], acc[m][n], 0, 0, 0);
        }
    };

    const int nt = J.K / 64;   // >= 8 for all jobs
    stage(0, 0);
    stage(1, 64);
    int cb = 0;  // t % 3
    for (int t = 0; t < nt - 1; ++t) {
        // wait for stage(t) only: newest 6 loads (stage(t+1)) may stay in flight
        asm volatile("s_waitcnt vmcnt(6)" ::: "memory");
        __builtin_amdgcn_sched_barrier(0);
        __builtin_amdgcn_s_barrier();
        __builtin_amdgcn_sched_barrier(0);
        if (t + 2 < nt) {
            int sb = cb + 2 >= 3 ? cb - 1 : cb + 2;
            stage(sb, (t + 2) * 64);   // issued early; lands by iter t+2's wait
        }
        compute(cb);
        cb = (cb + 1 == 3) ? 0 : cb + 1;
    }
    asm volatile("s_waitcnt vmcnt(0)" ::: "memory");  // last tile: nothing newer in flight
    __builtin_amdgcn_sched_barrier(0);
    __builtin_amdgcn_s_barrier();
    __builtin_amdgcn_sched_barrier(0);
    compute(cb);
    __syncthreads();  // all waves done with LDS frag reads (before smem reuse)

    if (J.mode == 3 && nb >= 1024) {
        // V half: stage [col_local 0..127][row_local 0..63] (stride 72), then
        // write vtcT rows coalesced.
        _Float16* T = (_Float16*)smem;
#pragma unroll
        for (int n = 0; n < 4; ++n) {
            int cl = wc + n * 16 + lr;
            float bv = J.bias[nb + cl];
#pragma unroll
            for (int m = 0; m < 2; ++m)
#pragma unroll
                for (int r = 0; r < 4; ++r)
                    T[cl * 72 + wr + m * 16 + lg * 4 + r] =
                        (_Float16)((acc[m][n][r] + bv) * J.scale);
        }
        __syncthreads();
        const int vd   = tid >> 1;       // 0..127 local v-dim
        const int half = tid & 1;        // 32-elem half of the 64 rows
        _Float16* dst = (_Float16*)J.C1 + (size_t)(nb - 1024 + vd) * Rtot + mb + half * 32;
        const _Float16* srcT = T + vd * 72 + half * 32;
#pragma unroll
        for (int j = 0; j < 4; ++j)
            *(f16x8*)&dst[j * 8] = *(const f16x8*)&srcT[j * 8];
        return;
    }

#pragma unroll
    for (int n = 0; n < 4; ++n) {
        int col  = nb + wc + n * 16 + lr;
        float bv = J.bias ? J.bias[col] : 0.0f;
        bool doRope = (J.mode == 4 && col >= 1024) ||
                      (J.mode == 5 && col >= 512 && col < 576);
#pragma unroll
        for (int m = 0; m < 2; ++m) {
#pragma unroll
            for (int r = 0; r < 4; ++r) {
                int row    = mb + wr + m * 16 + lg * 4 + r;
                float val  = (acc[m][n][r] + bv) * J.scale;
                if (doRope) val = rope_val(val, col, row, Smask);
                if (J.mode == 1)      ((float*)J.C0)[(size_t)row * J.ldc + col] = val;
                else if (J.mode == 3) ((__hip_bfloat16*)J.C0)[(size_t)row * 1024 + col] = __float2bfloat16(val);
                else                  ((__hip_bfloat16*)J.C0)[(size_t)row * J.ldc + col] = __float2bfloat16(val);
            }
        }
    }
}

// ---------- Flash attention (R12/R13 structure, unchanged): 8-wave blocks, dbuf, no-max softmax ----------
__global__ __launch_bounds__(512, 4) void attn_kernel(const __hip_bfloat16* __restrict__ qcat,
                                                      const __hip_bfloat16* __restrict__ ktc,
                                                      const __hip_bfloat16* __restrict__ kr,
                                                      const _Float16* __restrict__ vtcT,
                                                      __hip_bfloat16* __restrict__ outp,
                                                      int S, int R) {
    __shared__ __align__(16) char lds[2][24 * 1024];  // [K 16KB | V 8KB] x 2
    const int tid  = threadIdx.x;
    const int wid  = tid >> 6;       // 0..7
    const int lane = tid & 63;
    const int lr   = lane & 15;
    const int lg   = lane >> 4;

    const int NQ   = S / 128;
    const int L    = blockIdx.x;
    const int slot = L >> 3;
    const int gg   = (L & 7) + 8 * (slot / NQ);
    const int qt   = slot % NQ;
    const int h    = gg & 15;
    const int b    = gg >> 4;
    const size_t base = (size_t)b * S;
    const int qb   = qt * 128 + wid * 16;   // wave's 16 q rows

    auto stage = [&](int bufi, int kt) {
        char* bufK = lds[bufi];
        char* bufV = lds[bufi] + 16 * 1024;
#pragma unroll
        for (int j = 0; j < 2; ++j) {  // K: 16 chunks of 1KB, 2 per wave
            int c   = wid * 2 + j;
            int rho = c * 4 + (lane >> 4);
            int u   = (lane & 15) ^ (rho & 15);   // logical 16B slot (4-bit swizzle)
            const __hip_bfloat16* src = (u < 8)
                ? ktc + (base + kt + rho) * 1024 + h * 64 + u * 8
                : kr  + (base + kt + rho) * 640 + (u & 7) * 8;
            gload_lds16(src, bufK + c * 1024);
        }
        {   // V^T: 8 chunks of 1KB, 1 per wave
            int c   = wid;
            int rho = c * 8 + (lane >> 3);
            int u   = (lane & 7) ^ (rho & 7);
            gload_lds16(vtcT + (size_t)(h * 64 + rho) * R + base + kt + u * 8,
                        bufV + c * 1024);
        }
    };

    // Q fragments (registers, whole kernel): 16 q rows x 128 dims
    bf16x8 qf[4];
    {
        size_t row = base + qb + lr;
        const __hip_bfloat16* pq = qcat + row * 2048 + h * 64;
        qf[0] = *(const bf16x8*)(pq + lg * 8);
        qf[1] = *(const bf16x8*)(pq + 32 + lg * 8);
        qf[2] = *(const bf16x8*)(pq + 1024 + lg * 8);
        qf[3] = *(const bf16x8*)(pq + 1024 + 32 + lg * 8);
    }

    // hoisted LDS read offsets (constant per lane across tiles)
    int kbase[4], vbase[4];
#pragma unroll
    for (int c = 0; c < 4; ++c)
        kbase[c] = lr * 256 + (((c * 4 + lg) ^ lr) << 4);
#pragma unroll
    for (int st = 0; st < 4; ++st)
        vbase[st] = lr * 128 + ((((st * 2 + (lg >> 1)) ^ (lr & 7)) << 4) + (lg & 1) * 8);

    f32x4 oacc[4] = {};
    float lrun = 0.0f;
#if __has_builtin(__builtin_amdgcn_fdot2)
    fp16x2_raw one2;
    one2[0] = (__fp16)1.0f; one2[1] = (__fp16)1.0f;
#endif

    const int NT = S / 64;
    stage(0, 0);
    __syncthreads();

    for (int t = 0; t < NT; ++t) {
        const int cur = t & 1;
        if (t + 1 < NT) stage(cur ^ 1, (t + 1) * 64);

        const char* bufK = lds[cur];
        const char* bufV = lds[cur] + 16 * 1024;

        // QK^T (swapped operands: K as A -> C col=q, row=key)
        f32x4 sacc[4] = {};
        __builtin_amdgcn_s_setprio(1);
#pragma unroll
        for (int st = 0; st < 4; ++st)
#pragma unroll
            for (int c = 0; c < 4; ++c) {
                bf16x8 kf = *(const bf16x8*)(bufK + st * 4096 + kbase[c]);
                sacc[st] = __builtin_amdgcn_mfma_f32_16x16x32_bf16(kf, qf[c], sacc[st], 0, 0, 0);
            }
        __builtin_amdgcn_s_setprio(0);

        // softmax (no max: p = exp2(s) directly) + PV
        float p[4][4];
#pragma unroll
        for (int st = 0; st < 4; ++st)
#pragma unroll
            for (int r = 0; r < 4; ++r)
                p[st][r] = __builtin_exp2f(sacc[st][r]);
        __builtin_amdgcn_s_setprio(1);
#pragma unroll
        for (int st = 0; st < 4; ++st) {
            union { fp16x2_raw h2[2]; f16x4 v; } pu;
            pu.h2[0] = __builtin_amdgcn_cvt_pkrtz(p[st][0], p[st][1]);
            pu.h2[1] = __builtin_amdgcn_cvt_pkrtz(p[st][2], p[st][3]);
#if __has_builtin(__builtin_amdgcn_fdot2)
            lrun = __builtin_amdgcn_fdot2(pu.h2[0], one2, lrun, false);
            lrun = __builtin_amdgcn_fdot2(pu.h2[1], one2, lrun, false);
#else
            lrun += p[st][0] + p[st][1] + p[st][2] + p[st][3];
#endif
#pragma unroll
            for (int vt = 0; vt < 4; ++vt) {
                f16x4 vf = *(const f16x4*)(bufV + vt * 2048 + vbase[st]);
                oacc[vt] = __builtin_amdgcn_mfma_f32_16x16x16f16(vf, pu.v, oacc[vt], 0, 0, 0);
            }
        }
        __builtin_amdgcn_s_setprio(0);
        __syncthreads();  // drains staging loads + all waves' LDS reads
    }

    // epilogue: cross-lane l reduce, normalize, store bf16
    lrun += __shfl_xor(lrun, 16);
    lrun += __shfl_xor(lrun, 32);
    float inv = 1.0f / lrun;
    size_t rowoff = (base + qb + lr) << 10;
#pragma unroll
    for (int vt = 0; vt < 4; ++vt)
#pragma unroll
        for (int r = 0; r < 4; ++r)
            outp[rowoff + h * 64 + vt * 16 + lg * 4 + r] =
                __float2bfloat16(oacc[vt][r] * inv);
}

// ---------- launch ----------
extern "C" void kernel_launch(void* const* d_in, const int* in_sizes, int n_in,
                              void* d_out, int out_size, void* d_ws, size_t ws_size,
                              hipStream_t stream) {
    const float* query = (const float*)d_in[0];
    const float* key   = (const float*)d_in[1];
    const float* w_dkv = (const float*)d_in[3];
    const float* b_dkv = (const float*)d_in[4];
    const float* w_uk  = (const float*)d_in[5];
    const float* b_uk  = (const float*)d_in[6];
    const float* w_uv  = (const float*)d_in[7];
    const float* b_uv  = (const float*)d_in[8];
    const float* w_dq  = (const float*)d_in[9];
    const float* b_dq  = (const float*)d_in[10];
    const float* w_uq  = (const float*)d_in[11];
    const float* b_uq  = (const float*)d_in[12];
    const float* w_qr  = (const float*)d_in[13];
    const float* b_qr  = (const float*)d_in[14];
    const float* w_kr  = (const float*)d_in[15];
    const float* b_kr  = (const float*)d_in[16];
    const float* w_fc  = (const float*)d_in[17];
    const float* b_fc  = (const float*)d_in[18];

    const int B = 2;
    const int R = in_sizes[0] / 1024;  // B*S = 4096
    const int S = R / B;               // 2048 (power of two)
    const float QSCALE = 1.4426950408889634f / 16.0f;  // log2e / (sqrt(64)+sqrt(64))

    char* ws = (char*)d_ws;
    size_t off = 0;
    auto alloc = [&](size_t bytes) -> char* {
        char* p = ws + off;
        off += (bytes + 255) & ~(size_t)255;
        return p;
    };

    __hip_bfloat16* q_bf  = (__hip_bfloat16*)alloc((size_t)R * 1024 * 2);
    __hip_bfloat16* k_bf  = (__hip_bfloat16*)alloc((size_t)R * 1024 * 2);
    __hip_bfloat16* wcat1 = (__hip_bfloat16*)alloc(640 * 1024 * 2);    // [dkv(512); kr pad(128)] x K=1024
    __hip_bfloat16* wdq_t = (__hip_bfloat16*)alloc(512 * 1024 * 2);
    __hip_bfloat16* wcat3 = (__hip_bfloat16*)alloc(2048 * 512 * 2);    // [uk(1024); uv(1024)] x K=512
    __hip_bfloat16* wcat2 = (__hip_bfloat16*)alloc(2048 * 512 * 2);    // [uq(1024); qr(1024)] x K=512
    __hip_bfloat16* wfc_t = (__hip_bfloat16*)alloc(1024 * 1024 * 2);
    float*          bcat1 = (float*)alloc(640 * 4);
    float*          bcat2 = (float*)alloc(2048 * 4);
    float*          bcat3 = (float*)alloc(2048 * 4);
    __hip_bfloat16* ckkr  = (__hip_bfloat16*)alloc((size_t)R * 640 * 2);   // [c_kv(512) | krope(128)]
    __hip_bfloat16* c_q   = (__hip_bfloat16*)alloc((size_t)R * 512 * 2);
    __hip_bfloat16* ktc   = (__hip_bfloat16*)alloc((size_t)R * 1024 * 2);
    _Float16*       vtcT  = (_Float16*)alloc((size_t)R * 1024 * 2);        // [1024][R], written by GEMM B
    __hip_bfloat16* qcat  = (__hip_bfloat16*)alloc((size_t)R * 2048 * 2);  // [qtc(1024) | qrope(1024)]
    __hip_bfloat16* attn_out = q_bf;  // alias: q_bf dead after gemmA

    // 1) mega-prep: input cvt + weight transposes + bias concats
    PrepArgs PA;
    PA.query = query; PA.key = key; PA.q_bf = q_bf; PA.k_bf = k_bf;
    PA.n8 = R * 1024 / 8;
    PA.cvtBlocks = 2 * PA.n8 / 256;
    PA.j[0] = {w_dkv, wcat1,              1024, 512,  16};
    PA.j[1] = {w_kr,  wcat1 + 512 * 1024, 1024, 64,   16};
    PA.j[2] = {w_dq,  wdq_t,              1024, 512,  16};
    PA.j[3] = {w_uk,  wcat3,              512,  1024, 8};
    PA.j[4] = {w_uv,  wcat3 + 1024 * 512, 512,  1024, 8};
    PA.j[5] = {w_uq,  wcat2,              512,  1024, 8};
    PA.j[6] = {w_qr,  wcat2 + 1024 * 512, 512,  1024, 8};
    PA.j[7] = {w_fc,  wfc_t,              1024, 1024, 16};
    {
        int st = 0;
        const int counts[8] = {128, 32, 128, 128, 128, 128, 128, 256};
        for (int i = 0; i < 8; ++i) { PA.start[i] = st; st += counts[i]; }
        PA.tBlocks = st;
    }
    PA.b_dkv = b_dkv; PA.b_kr = b_kr; PA.b_uk = b_uk; PA.b_uv = b_uv;
    PA.b_uq = b_uq;   PA.b_qr = b_qr;
    PA.bcat1 = bcat1; PA.bcat2 = bcat2; PA.bcat3 = bcat3;
    prep_kernel<<<dim3(PA.cvtBlocks + PA.tBlocks + 19), 256, 0, stream>>>(PA);

    // 2) down-projections: cat1 (k -> [c_kv|krope], krope roped in epilogue) + dq
    GJob ja0 = {k_bf, wcat1, bcat1, ckkr, nullptr, 640, 1024, 1024, 1024, 640, 1.0f, 5};
    GJob ja1 = {q_bf, wdq_t, b_dq,  c_q,  nullptr, 512, 1024, 1024, 1024, 512, 1.0f, 0};
    gemm64<<<dim3(9, R / 64), 256, 0, stream>>>(ja0, ja1, 5, S - 1, R);

    // 3) up-projections: ukuv (ckkr -> ktc | vtcT transposed-in-epilogue)
    //    + uqqr (c_q -> qcat, pre-scaled by QSCALE, qrope roped in epilogue)
    GJob jb0 = {ckkr, wcat3, bcat3, ktc,  vtcT,    2048, 512, 640, 512, 1024, 1.0f,   3};
    GJob jb1 = {c_q,  wcat2, bcat2, qcat, nullptr, 2048, 512, 512, 512, 2048, QSCALE, 4};
    gemm64<<<dim3(32, R / 64), 256, 0, stream>>>(jb0, jb1, 16, S - 1, R);

    // 4) attention (1D grid, XCD-grouped; 512-thread blocks)
    attn_kernel<<<dim3((S / 128) * 16 * B), 512, 0, stream>>>(qcat, ktc, ckkr + 512, vtcT, attn_out, S, R);

    // 5) output projection (f32 to d_out)
    GJob jc0 = {attn_out, wfc_t, b_fc, d_out, nullptr, 1024, 1024, 1024, 1024, 1024, 1.0f, 1};
    gemm64<<<dim3(8, R / 64), 256, 0, stream>>>(jc0, jc0, 8, S - 1, R);
}

// Round 16
// 177.006 us; speedup vs baseline: 1.0461x; 1.0461x over previous
//
#include <hip/hip_runtime.h>
#include <hip/hip_bf16.h>
#include <hip/hip_fp16.h>

// ---------- types ----------
typedef __attribute__((ext_vector_type(8))) short    bf16x8;  // 8 bf16 MFMA A/B frag
typedef __attribute__((ext_vector_type(4))) float    f32x4;   // MFMA C/D frag
typedef __attribute__((ext_vector_type(4))) _Float16 f16x4;   // 16x16x16 f16 frag
typedef __attribute__((ext_vector_type(8))) _Float16 f16x8;
typedef __attribute__((ext_vector_type(2))) __fp16   fp16x2_raw;  // cvt_pkrtz return type

typedef const void __attribute__((address_space(1))) gvoid_t;
typedef void __attribute__((address_space(3)))       lvoid_t;

static __device__ __forceinline__ void gload_lds16(const void* g, void* l) {
    // LDS dest = wave-uniform base + lane*16B; global src is per-lane.
    __builtin_amdgcn_global_load_lds((gvoid_t*)g, (lvoid_t*)l, 16, 0, 0);
}

static __device__ __forceinline__ short bfbits(float f) {
    union { __hip_bfloat16 h; short s; } u;
    u.h = __float2bfloat16(f);
    return u.s;
}

// RoPE rotation shared by GEMM epilogues. Reference quirk preserved:
// out[2i] = x0*sin(pe) - x1*cos(pe); out[2i+1] = x1*sin(pe) + x0*cos(pe).
static __device__ __forceinline__ float rope_val(float val, int col, int row, int Smask) {
    float other = __shfl_xor(val, 1);
    float theta = __expf(-0.28782313662425572f * (float)((col >> 1) & 31));
    float sp, cp;
    __sincosf((float)(row & Smask) * theta, &sp, &cp);
    return (col & 1) ? fmaf(val, sp, other * cp) : fmaf(val, sp, -other * cp);
}

// ---------- mega-prep: input cvt + 8 weight transposes + bias concats, one launch ----------
struct TJob { const float* src; __hip_bfloat16* dst; int K, N, tx; };
struct PrepArgs {
    const float* query; const float* key;
    __hip_bfloat16* q_bf; __hip_bfloat16* k_bf; int n8; int cvtBlocks; int tBlocks;
    TJob j[8]; int start[8];
    const float *b_dkv, *b_kr, *b_uk, *b_uv, *b_uq, *b_qr;
    float *bcat1, *bcat2, *bcat3;
};

__global__ __launch_bounds__(256) void prep_kernel(PrepArgs A) {
    __shared__ __hip_bfloat16 tile[64][72];
    int bid = blockIdx.x;
    if (bid < A.cvtBlocks) {
        int t = bid * 256 + threadIdx.x;
        const float* src;
        __hip_bfloat16* dst;
        int i;
        if (t < A.n8) { src = A.query; dst = A.q_bf; i = t; }
        else          { src = A.key;   dst = A.k_bf; i = t - A.n8; }
        float4 a = ((const float4*)src)[2 * i];
        float4 b = ((const float4*)src)[2 * i + 1];
        bf16x8 o;
        o[0] = bfbits(a.x); o[1] = bfbits(a.y); o[2] = bfbits(a.z); o[3] = bfbits(a.w);
        o[4] = bfbits(b.x); o[5] = bfbits(b.y); o[6] = bfbits(b.z); o[7] = bfbits(b.w);
        ((bf16x8*)dst)[i] = o;
        return;
    }
    bid -= A.cvtBlocks;
    if (bid < A.tBlocks) {
        int ji = 0;
#pragma unroll
        for (int k = 1; k < 8; ++k) if (bid >= A.start[k]) ji = k;
        const TJob J = A.j[ji];
        const int local = bid - A.start[ji];
        const int kb = (local % J.tx) * 64;
        const int nb = (local / J.tx) * 64;
        const int c  = threadIdx.x & 63;
        const int r0 = threadIdx.x >> 6;
        if (nb < J.N) {
#pragma unroll
            for (int i = 0; i < 16; ++i) {
                int r = r0 + i * 4;
                tile[r][c] = __float2bfloat16(J.src[(size_t)(kb + r) * J.N + nb + c]);
            }
            __syncthreads();
#pragma unroll
            for (int i = 0; i < 16; ++i) {
                int r = r0 + i * 4;
                J.dst[(size_t)(nb + r) * J.K + kb + c] = tile[c][r];
            }
        } else {
            __hip_bfloat16 z = __float2bfloat16(0.0f);
#pragma unroll
            for (int i = 0; i < 16; ++i) {
                int r = r0 + i * 4;
                J.dst[(size_t)(nb + r) * J.K + kb + c] = z;
            }
        }
        return;
    }
    bid -= A.tBlocks;
    int t = bid * 256 + threadIdx.x;
    if (t < 640) {
        A.bcat1[t] = (t < 512) ? A.b_dkv[t] : ((t - 512) < 64 ? A.b_kr[t - 512] : 0.0f);
    } else if (t < 2688) {
        int u = t - 640;
        A.bcat2[u] = (u < 1024) ? A.b_uq[u] : A.b_qr[u - 1024];
    } else if (t < 4736) {
        int u = t - 2688;
        A.bcat3[u] = (u < 1024) ? A.b_uk[u] : A.b_uv[u - 1024];
    }
}

// ---------- unified dual-job GEMM: 64x128 tile, BK=64, dbuf, XOR-swizzled LDS ----------
// modes: 0 = bf16 -> C0
//        1 = f32  -> C0
//        3 = cols<1024 bf16 -> C0 (ktc); cols>=1024 -> C1 = vtcT [1024][Rtot] f16,
//            written TRANSPOSED via in-block LDS transpose
//        4 = bf16 -> C0, RoPE on cols>=1024 (qrope)
//        5 = bf16 -> C0, RoPE on cols in [512,576) (krope)
// LDS layout: row-major tiles; 16B slot s of row r holds global slot s^(r&7)
// (stage pre-swizzles the GLOBAL src; reads XOR the slot -- rule 21, conflict-free).
struct GJob {
    const __hip_bfloat16* A; const __hip_bfloat16* Bt; const float* bias;
    void* C0; void* C1; int N, K, lda, ldb, ldc; float scale; int mode;
};

__global__ __launch_bounds__(256) void gemm64(GJob j0, GJob j1, int split, int Smask, int Rtot) {
    __shared__ __align__(16) char smem[49152];             // sA 16KB | sB 32KB; T aliases
    __hip_bfloat16* sA = (__hip_bfloat16*)smem;            // [2][64*64]
    __hip_bfloat16* sB = (__hip_bfloat16*)(smem + 16384);  // [2][128*64]
    const GJob J  = (blockIdx.x < (unsigned)split) ? j0 : j1;
    const int bx  = (blockIdx.x < (unsigned)split) ? blockIdx.x : blockIdx.x - split;
    const int tid  = threadIdx.x;
    const int wid  = tid >> 6;
    const int lane = tid & 63;
    const int lr   = lane & 15;
    const int lg   = lane >> 4;
    const int mb   = blockIdx.y * 64;
    const int nb   = bx * 128;
    const int wr   = (wid >> 1) * 32;
    const int wc   = (wid & 1) * 64;

    auto stage = [&](int bufi, int k0) {
#pragma unroll
        for (int j = 0; j < 2; ++j) {  // A tile 64x64: 8 chunks of 1KB (8 rows), 2 per wave
            int c   = wid * 2 + j;
            int rho = c * 8 + (lane >> 3);
            int u   = (lane & 7) ^ (rho & 7);
            gload_lds16(J.A + (size_t)(mb + rho) * J.lda + (k0 + u * 8),
                        &sA[bufi * 4096 + c * 512]);
        }
#pragma unroll
        for (int j = 0; j < 4; ++j) {  // B tile 128x64: 16 chunks, 4 per wave
            int c   = wid * 4 + j;
            int rho = c * 8 + (lane >> 3);
            int u   = (lane & 7) ^ (rho & 7);
            gload_lds16(J.Bt + (size_t)(nb + rho) * J.ldb + (k0 + u * 8),
                        &sB[bufi * 8192 + c * 512]);
        }
    };

    f32x4 acc[2][4] = {};
    const int nt = J.K / 64;
    stage(0, 0);
    asm volatile("s_waitcnt vmcnt(0)" ::: "memory");
    __syncthreads();

    for (int t = 0; t < nt; ++t) {
        const int cur = t & 1;
        if (t + 1 < nt) stage(cur ^ 1, (t + 1) * 64);  // loads in flight over MFMA
#pragma unroll
        for (int kk = 0; kk < 2; ++kk) {
            bf16x8 af[2], bfr[4];
#pragma unroll
            for (int m = 0; m < 2; ++m) {
                int row = wr + m * 16 + lr;
                af[m] = *(const bf16x8*)&sA[cur * 4096 + row * 64 + (((kk * 4 + lg) ^ (row & 7)) << 3)];
            }
#pragma unroll
            for (int n = 0; n < 4; ++n) {
                int row = wc + n * 16 + lr;
                bfr[n] = *(const bf16x8*)&sB[cur * 8192 + row * 64 + (((kk * 4 + lg) ^ (row & 7)) << 3)];
            }
#pragma unroll
            for (int m = 0; m < 2; ++m)
#pragma unroll
                for (int n = 0; n < 4; ++n)
                    acc[m][n] = __builtin_amdgcn_mfma_f32_16x16x32_bf16(af[m], bfr[n], acc[m][n], 0, 0, 0);
        }
        asm volatile("s_waitcnt vmcnt(0)" ::: "memory");
        __syncthreads();
    }

    if (J.mode == 3 && nb >= 1024) {
        // V half: stage [col_local 0..127][row_local 0..63] (stride 72), then
        // write vtcT rows coalesced. sA/sB dead after final loop barrier.
        _Float16* T = (_Float16*)smem;
#pragma unroll
        for (int n = 0; n < 4; ++n) {
            int cl = wc + n * 16 + lr;
            float bv = J.bias[nb + cl];
#pragma unroll
            for (int m = 0; m < 2; ++m)
#pragma unroll
                for (int r = 0; r < 4; ++r)
                    T[cl * 72 + wr + m * 16 + lg * 4 + r] =
                        (_Float16)((acc[m][n][r] + bv) * J.scale);
        }
        __syncthreads();
        const int vd   = tid >> 1;       // 0..127 local v-dim
        const int half = tid & 1;        // 32-elem half of the 64 rows
        _Float16* dst = (_Float16*)J.C1 + (size_t)(nb - 1024 + vd) * Rtot + mb + half * 32;
        const _Float16* srcT = T + vd * 72 + half * 32;
#pragma unroll
        for (int j = 0; j < 4; ++j)
            *(f16x8*)&dst[j * 8] = *(const f16x8*)&srcT[j * 8];
        return;
    }

#pragma unroll
    for (int n = 0; n < 4; ++n) {
        int col  = nb + wc + n * 16 + lr;
        float bv = J.bias ? J.bias[col] : 0.0f;
        bool doRope = (J.mode == 4 && col >= 1024) ||
                      (J.mode == 5 && col >= 512 && col < 576);
#pragma unroll
        for (int m = 0; m < 2; ++m) {
#pragma unroll
            for (int r = 0; r < 4; ++r) {
                int row    = mb + wr + m * 16 + lg * 4 + r;
                float val  = (acc[m][n][r] + bv) * J.scale;
                if (doRope) val = rope_val(val, col, row, Smask);
                if (J.mode == 1)      ((float*)J.C0)[(size_t)row * J.ldc + col] = val;
                else if (J.mode == 3) ((__hip_bfloat16*)J.C0)[(size_t)row * 1024 + col] = __float2bfloat16(val);
                else                  ((__hip_bfloat16*)J.C0)[(size_t)row * J.ldc + col] = __float2bfloat16(val);
            }
        }
    }
}

// ---------- Flash attention (R12/R13 structure, unchanged): 8-wave blocks, dbuf, no-max softmax ----------
__global__ __launch_bounds__(512, 4) void attn_kernel(const __hip_bfloat16* __restrict__ qcat,
                                                      const __hip_bfloat16* __restrict__ ktc,
                                                      const __hip_bfloat16* __restrict__ kr,
                                                      const _Float16* __restrict__ vtcT,
                                                      __hip_bfloat16* __restrict__ outp,
                                                      int S, int R) {
    __shared__ __align__(16) char lds[2][24 * 1024];  // [K 16KB | V 8KB] x 2
    const int tid  = threadIdx.x;
    const int wid  = tid >> 6;       // 0..7
    const int lane = tid & 63;
    const int lr   = lane & 15;
    const int lg   = lane >> 4;

    const int NQ   = S / 128;
    const int L    = blockIdx.x;
    const int slot = L >> 3;
    const int gg   = (L & 7) + 8 * (slot / NQ);
    const int qt   = slot % NQ;
    const int h    = gg & 15;
    const int b    = gg >> 4;
    const size_t base = (size_t)b * S;
    const int qb   = qt * 128 + wid * 16;   // wave's 16 q rows

    auto stage = [&](int bufi, int kt) {
        char* bufK = lds[bufi];
        char* bufV = lds[bufi] + 16 * 1024;
#pragma unroll
        for (int j = 0; j < 2; ++j) {  // K: 16 chunks of 1KB, 2 per wave
            int c   = wid * 2 + j;
            int rho = c * 4 + (lane >> 4);
            int u   = (lane & 15) ^ (rho & 15);   // logical 16B slot (4-bit swizzle)
            const __hip_bfloat16* src = (u < 8)
                ? ktc + (base + kt + rho) * 1024 + h * 64 + u * 8
                : kr  + (base + kt + rho) * 640 + (u & 7) * 8;
            gload_lds16(src, bufK + c * 1024);
        }
        {   // V^T: 8 chunks of 1KB, 1 per wave
            int c   = wid;
            int rho = c * 8 + (lane >> 3);
            int u   = (lane & 7) ^ (rho & 7);
            gload_lds16(vtcT + (size_t)(h * 64 + rho) * R + base + kt + u * 8,
                        bufV + c * 1024);
        }
    };

    // Q fragments (registers, whole kernel): 16 q rows x 128 dims
    bf16x8 qf[4];
    {
        size_t row = base + qb + lr;
        const __hip_bfloat16* pq = qcat + row * 2048 + h * 64;
        qf[0] = *(const bf16x8*)(pq + lg * 8);
        qf[1] = *(const bf16x8*)(pq + 32 + lg * 8);
        qf[2] = *(const bf16x8*)(pq + 1024 + lg * 8);
        qf[3] = *(const bf16x8*)(pq + 1024 + 32 + lg * 8);
    }

    // hoisted LDS read offsets (constant per lane across tiles)
    int kbase[4], vbase[4];
#pragma unroll
    for (int c = 0; c < 4; ++c)
        kbase[c] = lr * 256 + (((c * 4 + lg) ^ lr) << 4);
#pragma unroll
    for (int st = 0; st < 4; ++st)
        vbase[st] = lr * 128 + ((((st * 2 + (lg >> 1)) ^ (lr & 7)) << 4) + (lg & 1) * 8);

    f32x4 oacc[4] = {};
    float lrun = 0.0f;
#if __has_builtin(__builtin_amdgcn_fdot2)
    fp16x2_raw one2;
    one2[0] = (__fp16)1.0f; one2[1] = (__fp16)1.0f;
#endif

    const int NT = S / 64;
    stage(0, 0);
    __syncthreads();

    for (int t = 0; t < NT; ++t) {
        const int cur = t & 1;
        if (t + 1 < NT) stage(cur ^ 1, (t + 1) * 64);

        const char* bufK = lds[cur];
        const char* bufV = lds[cur] + 16 * 1024;

        // QK^T (swapped operands: K as A -> C col=q, row=key)
        f32x4 sacc[4] = {};
        __builtin_amdgcn_s_setprio(1);
#pragma unroll
        for (int st = 0; st < 4; ++st)
#pragma unroll
            for (int c = 0; c < 4; ++c) {
                bf16x8 kf = *(const bf16x8*)(bufK + st * 4096 + kbase[c]);
                sacc[st] = __builtin_amdgcn_mfma_f32_16x16x32_bf16(kf, qf[c], sacc[st], 0, 0, 0);
            }
        __builtin_amdgcn_s_setprio(0);

        // softmax (no max: p = exp2(s) directly) + PV
        float p[4][4];
#pragma unroll
        for (int st = 0; st < 4; ++st)
#pragma unroll
            for (int r = 0; r < 4; ++r)
                p[st][r] = __builtin_exp2f(sacc[st][r]);
        __builtin_amdgcn_s_setprio(1);
#pragma unroll
        for (int st = 0; st < 4; ++st) {
            union { fp16x2_raw h2[2]; f16x4 v; } pu;
            pu.h2[0] = __builtin_amdgcn_cvt_pkrtz(p[st][0], p[st][1]);
            pu.h2[1] = __builtin_amdgcn_cvt_pkrtz(p[st][2], p[st][3]);
#if __has_builtin(__builtin_amdgcn_fdot2)
            lrun = __builtin_amdgcn_fdot2(pu.h2[0], one2, lrun, false);
            lrun = __builtin_amdgcn_fdot2(pu.h2[1], one2, lrun, false);
#else
            lrun += p[st][0] + p[st][1] + p[st][2] + p[st][3];
#endif
#pragma unroll
            for (int vt = 0; vt < 4; ++vt) {
                f16x4 vf = *(const f16x4*)(bufV + vt * 2048 + vbase[st]);
                oacc[vt] = __builtin_amdgcn_mfma_f32_16x16x16f16(vf, pu.v, oacc[vt], 0, 0, 0);
            }
        }
        __builtin_amdgcn_s_setprio(0);
        __syncthreads();  // drains staging loads + all waves' LDS reads
    }

    // epilogue: cross-lane l reduce, normalize, store bf16
    lrun += __shfl_xor(lrun, 16);
    lrun += __shfl_xor(lrun, 32);
    float inv = 1.0f / lrun;
    size_t rowoff = (base + qb + lr) << 10;
#pragma unroll
    for (int vt = 0; vt < 4; ++vt)
#pragma unroll
        for (int r = 0; r < 4; ++r)
            outp[rowoff + h * 64 + vt * 16 + lg * 4 + r] =
                __float2bfloat16(oacc[vt][r] * inv);
}

// ---------- launch ----------
extern "C" void kernel_launch(void* const* d_in, const int* in_sizes, int n_in,
                              void* d_out, int out_size, void* d_ws, size_t ws_size,
                              hipStream_t stream) {
    const float* query = (const float*)d_in[0];
    const float* key   = (const float*)d_in[1];
    const float* w_dkv = (const float*)d_in[3];
    const float* b_dkv = (const float*)d_in[4];
    const float* w_uk  = (const float*)d_in[5];
    const float* b_uk  = (const float*)d_in[6];
    const float* w_uv  = (const float*)d_in[7];
    const float* b_uv  = (const float*)d_in[8];
    const float* w_dq  = (const float*)d_in[9];
    const float* b_dq  = (const float*)d_in[10];
    const float* w_uq  = (const float*)d_in[11];
    const float* b_uq  = (const float*)d_in[12];
    const float* w_qr  = (const float*)d_in[13];
    const float* b_qr  = (const float*)d_in[14];
    const float* w_kr  = (const float*)d_in[15];
    const float* b_kr  = (const float*)d_in[16];
    const float* w_fc  = (const float*)d_in[17];
    const float* b_fc  = (const float*)d_in[18];

    const int B = 2;
    const int R = in_sizes[0] / 1024;  // B*S = 4096
    const int S = R / B;               // 2048 (power of two)
    const float QSCALE = 1.4426950408889634f / 16.0f;  // log2e / (sqrt(64)+sqrt(64))

    char* ws = (char*)d_ws;
    size_t off = 0;
    auto alloc = [&](size_t bytes) -> char* {
        char* p = ws + off;
        off += (bytes + 255) & ~(size_t)255;
        return p;
    };

    __hip_bfloat16* q_bf  = (__hip_bfloat16*)alloc((size_t)R * 1024 * 2);
    __hip_bfloat16* k_bf  = (__hip_bfloat16*)alloc((size_t)R * 1024 * 2);
    __hip_bfloat16* wcat1 = (__hip_bfloat16*)alloc(640 * 1024 * 2);    // [dkv(512); kr pad(128)] x K=1024
    __hip_bfloat16* wdq_t = (__hip_bfloat16*)alloc(512 * 1024 * 2);
    __hip_bfloat16* wcat3 = (__hip_bfloat16*)alloc(2048 * 512 * 2);    // [uk(1024); uv(1024)] x K=512
    __hip_bfloat16* wcat2 = (__hip_bfloat16*)alloc(2048 * 512 * 2);    // [uq(1024); qr(1024)] x K=512
    __hip_bfloat16* wfc_t = (__hip_bfloat16*)alloc(1024 * 1024 * 2);
    float*          bcat1 = (float*)alloc(640 * 4);
    float*          bcat2 = (float*)alloc(2048 * 4);
    float*          bcat3 = (float*)alloc(2048 * 4);
    __hip_bfloat16* ckkr  = (__hip_bfloat16*)alloc((size_t)R * 640 * 2);   // [c_kv(512) | krope(128)]
    __hip_bfloat16* c_q   = (__hip_bfloat16*)alloc((size_t)R * 512 * 2);
    __hip_bfloat16* ktc   = (__hip_bfloat16*)alloc((size_t)R * 1024 * 2);
    _Float16*       vtcT  = (_Float16*)alloc((size_t)R * 1024 * 2);        // [1024][R], written by GEMM B
    __hip_bfloat16* qcat  = (__hip_bfloat16*)alloc((size_t)R * 2048 * 2);  // [qtc(1024) | qrope(1024)]
    __hip_bfloat16* attn_out = q_bf;  // alias: q_bf dead after gemmA

    // 1) mega-prep: input cvt + weight transposes + bias concats
    PrepArgs PA;
    PA.query = query; PA.key = key; PA.q_bf = q_bf; PA.k_bf = k_bf;
    PA.n8 = R * 1024 / 8;
    PA.cvtBlocks = 2 * PA.n8 / 256;
    PA.j[0] = {w_dkv, wcat1,              1024, 512,  16};
    PA.j[1] = {w_kr,  wcat1 + 512 * 1024, 1024, 64,   16};
    PA.j[2] = {w_dq,  wdq_t,              1024, 512,  16};
    PA.j[3] = {w_uk,  wcat3,              512,  1024, 8};
    PA.j[4] = {w_uv,  wcat3 + 1024 * 512, 512,  1024, 8};
    PA.j[5] = {w_uq,  wcat2,              512,  1024, 8};
    PA.j[6] = {w_qr,  wcat2 + 1024 * 512, 512,  1024, 8};
    PA.j[7] = {w_fc,  wfc_t,              1024, 1024, 16};
    {
        int st = 0;
        const int counts[8] = {128, 32, 128, 128, 128, 128, 128, 256};
        for (int i = 0; i < 8; ++i) { PA.start[i] = st; st += counts[i]; }
        PA.tBlocks = st;
    }
    PA.b_dkv = b_dkv; PA.b_kr = b_kr; PA.b_uk = b_uk; PA.b_uv = b_uv;
    PA.b_uq = b_uq;   PA.b_qr = b_qr;
    PA.bcat1 = bcat1; PA.bcat2 = bcat2; PA.bcat3 = bcat3;
    prep_kernel<<<dim3(PA.cvtBlocks + PA.tBlocks + 19), 256, 0, stream>>>(PA);

    // 2) down-projections: cat1 (k -> [c_kv|krope], krope roped in epilogue) + dq
    GJob ja0 = {k_bf, wcat1, bcat1, ckkr, nullptr, 640, 1024, 1024, 1024, 640, 1.0f, 5};
    GJob ja1 = {q_bf, wdq_t, b_dq,  c_q,  nullptr, 512, 1024, 1024, 1024, 512, 1.0f, 0};
    gemm64<<<dim3(9, R / 64), 256, 0, stream>>>(ja0, ja1, 5, S - 1, R);

    // 3) up-projections: ukuv (ckkr -> ktc | vtcT transposed-in-epilogue)
    //    + uqqr (c_q -> qcat, pre-scaled by QSCALE, qrope roped in epilogue)
    GJob jb0 = {ckkr, wcat3, bcat3, ktc,  vtcT,    2048, 512, 640, 512, 1024, 1.0f,   3};
    GJob jb1 = {c_q,  wcat2, bcat2, qcat, nullptr, 2048, 512, 512, 512, 2048, QSCALE, 4};
    gemm64<<<dim3(32, R / 64), 256, 0, stream>>>(jb0, jb1, 16, S - 1, R);

    // 4) attention (1D grid, XCD-grouped; 512-thread blocks)
    attn_kernel<<<dim3((S / 128) * 16 * B), 512, 0, stream>>>(qcat, ktc, ckkr + 512, vtcT, attn_out, S, R);

    // 5) output projection (f32 to d_out)
    GJob jc0 = {attn_out, wfc_t, b_fc, d_out, nullptr, 1024, 1024, 1024, 1024, 1024, 1.0f, 1};
    gemm64<<<dim3(8, R / 64), 256, 0, stream>>>(jc0, jc0, 8, S - 1, R);
}